// Round 7
// baseline (30.126 us; speedup 1.0000x reference)
//
#include <hip/hip_runtime.h>

#define D_FEAT 128

// K1: per-node projection, 8-lane group per node (32 nodes / 256-thread block).
// pu[n] = h[n].Wu + b ; pv[n] = h[n].Wv
__global__ __launch_bounds__(256) void proj_kernel(
    const float* __restrict__ h,
    const float* __restrict__ W,
    const float* __restrict__ bptr,
    float* __restrict__ pu,
    float* __restrict__ pv,
    int n_nodes)
{
    const int t    = threadIdx.x & 7;
    const int node = blockIdx.x * 32 + (threadIdx.x >> 3);
    if (node >= n_nodes) return;

    const float4* W4 = (const float4*)W;
    float4 wu[4], wv[4];
    #pragma unroll
    for (int j = 0; j < 4; ++j) {
        wu[j] = W4[j * 8 + t];          // L1-resident after first wave
        wv[j] = W4[32 + j * 8 + t];
    }

    const float4* h4 = (const float4*)(h + (size_t)node * D_FEAT);
    float4 hv[4];
    #pragma unroll
    for (int j = 0; j < 4; ++j) hv[j] = h4[j * 8 + t];   // 64 B/lane in flight

    float su = 0.f, sv = 0.f;
    #pragma unroll
    for (int j = 0; j < 4; ++j) {
        su += hv[j].x*wu[j].x + hv[j].y*wu[j].y + hv[j].z*wu[j].z + hv[j].w*wu[j].w;
        sv += hv[j].x*wv[j].x + hv[j].y*wv[j].y + hv[j].z*wv[j].z + hv[j].w*wv[j].w;
    }
    #pragma unroll
    for (int off = 4; off > 0; off >>= 1) {   // xor 4,2,1: stays in 8-lane group
        su += __shfl_xor(su, off, 64);
        sv += __shfl_xor(sv, off, 64);
    }
    if (t == 0) {
        pu[node] = su + bptr[0];   // bias folded in: score = pu[src]+pv[dst]
        pv[node] = sv;
    }
}

// K2: 1 edge/thread, 3125 blocks (max TLP). Raw score -> out.
// Per-block min/max partials to DISTINCT addresses — no global atomics.
__global__ __launch_bounds__(256) void score_kernel(
    const int*   __restrict__ src,
    const int*   __restrict__ dst,
    const float* __restrict__ pu,
    const float* __restrict__ pv,
    float*       __restrict__ out,
    float*       __restrict__ pmin,
    float*       __restrict__ pmax,
    int n_edges)
{
    const int i = blockIdx.x * blockDim.x + threadIdx.x;
    float vmin =  3.4028235e38f;
    float vmax = -3.4028235e38f;
    if (i < n_edges) {
        const float s = pu[src[i]] + pv[dst[i]];   // pu/pv: 800 KB, L2-resident
        out[i] = s;
        vmin = s;
        vmax = s;
    }
    #pragma unroll
    for (int off = 32; off > 0; off >>= 1) {
        vmin = fminf(vmin, __shfl_xor(vmin, off, 64));
        vmax = fmaxf(vmax, __shfl_xor(vmax, off, 64));
    }
    __shared__ float smin[4], smax[4];
    const int w = threadIdx.x >> 6;
    if ((threadIdx.x & 63) == 0) { smin[w] = vmin; smax[w] = vmax; }
    __syncthreads();
    if (threadIdx.x == 0) {
        pmin[blockIdx.x] = fminf(fminf(smin[0], smin[1]), fminf(smin[2], smin[3]));
        pmax[blockIdx.x] = fmaxf(fmaxf(smax[0], smax[1]), fmaxf(smax[2], smax[3]));
    }
}

// K3: fused reduce+normalize. Every block redundantly reduces the nblk partial
// pairs (25 KB, L2-resident) then normalizes its float4 chunk of out in place.
__global__ __launch_bounds__(256) void norm_kernel(
    float* __restrict__ out,
    const float* __restrict__ pmin,
    const float* __restrict__ pmax,
    int nblk, int n4, int n_edges)
{
    float vmin =  3.4028235e38f;
    float vmax = -3.4028235e38f;
    for (int i = threadIdx.x; i < nblk; i += 256) {
        vmin = fminf(vmin, pmin[i]);
        vmax = fmaxf(vmax, pmax[i]);
    }
    #pragma unroll
    for (int off = 32; off > 0; off >>= 1) {
        vmin = fminf(vmin, __shfl_xor(vmin, off, 64));
        vmax = fmaxf(vmax, __shfl_xor(vmax, off, 64));
    }
    __shared__ float smin[4], smax[4];
    const int w = threadIdx.x >> 6;
    if ((threadIdx.x & 63) == 0) { smin[w] = vmin; smax[w] = vmax; }
    __syncthreads();
    // all threads compute the same final min/max from the 4 wave partials
    const float mn  = fminf(fminf(smin[0], smin[1]), fminf(smin[2], smin[3]));
    const float mx  = fmaxf(fmaxf(smax[0], smax[1]), fmaxf(smax[2], smax[3]));
    const float inv = 1.0f / (mx - mn);

    const int i = blockIdx.x * blockDim.x + threadIdx.x;
    if (i >= n4) return;
    float4 v = ((const float4*)out)[i];
    v.x = (v.x - mn) * inv;
    v.y = (v.y - mn) * inv;
    v.z = (v.z - mn) * inv;
    v.w = (v.w - mn) * inv;
    ((float4*)out)[i] = v;
    if (i == n4 - 1) {
        for (int e = n4 * 4; e < n_edges; ++e)
            out[e] = (out[e] - mn) * inv;
    }
}

extern "C" void kernel_launch(void* const* d_in, const int* in_sizes, int n_in,
                              void* d_out, int out_size, void* d_ws, size_t ws_size,
                              hipStream_t stream) {
    const float* h   = (const float*)d_in[0];
    const int*   src = (const int*)d_in[1];
    const int*   dst = (const int*)d_in[2];
    const float* W   = (const float*)d_in[3];
    const float* b   = (const float*)d_in[4];
    float* out = (float*)d_out;

    const int n_nodes = in_sizes[0] / D_FEAT;
    const int n_edges = in_sizes[1];

    const int blk2 = (n_edges + 255) / 256;    // 3125

    // workspace: pu[n_nodes], pv[n_nodes], pmin[blk2], pmax[blk2]
    float* ws   = (float*)d_ws;
    float* pu   = ws;
    float* pv   = ws + n_nodes;
    float* pmin = ws + 2 * n_nodes;
    float* pmax = pmin + blk2;

    // K1: 32 nodes / block -> 3125 blocks
    {
        const int blocks = (n_nodes + 31) / 32;
        proj_kernel<<<blocks, 256, 0, stream>>>(h, W, b, pu, pv, n_nodes);
    }
    // K2: 1 edge/thread -> 3125 blocks, no atomics
    score_kernel<<<blk2, 256, 0, stream>>>(src, dst, pu, pv, out, pmin, pmax, n_edges);
    // K3: fused partial-reduce + normalize
    {
        const int n4 = n_edges >> 2;           // 200000
        const int blocks = (n4 + 255) / 256;   // 782
        norm_kernel<<<blocks, 256, 0, stream>>>(out, pmin, pmax, blk2, n4, n_edges);
    }
}